// Round 6
// baseline (385.718 us; speedup 1.0000x reference)
//
#include <hip/hip_runtime.h>

typedef unsigned short u16;
typedef short bf16x8 __attribute__((ext_vector_type(8)));
typedef float f32x4 __attribute__((ext_vector_type(4)));

#define MFMA16(a, b, c) __builtin_amdgcn_mfma_f32_16x16x32_bf16((a), (b), (c), 0, 0, 0)

static __device__ __forceinline__ u16 f2bf(float f) {
    union { float f; unsigned int u; } v; v.f = f;
    unsigned int u = v.u;
    u += 0x7fffu + ((u >> 16) & 1u);   // round-to-nearest-even
    return (u16)(u >> 16);
}

// ---------------------------------------------------------------------------
// Prep: starts/counts via binary search + weights->bf16 + X->bf16 (if ws fits)
// ---------------------------------------------------------------------------
__global__ void prep_kernel(const int* __restrict__ bidx, int N,
                            const float* __restrict__ X,
                            const float* __restrict__ w_in, const float* __restrict__ w_out,
                            int* __restrict__ starts, int* __restrict__ counts,
                            u16* __restrict__ w_in_bf, u16* __restrict__ w_out_bf,
                            u16* __restrict__ xbf) {
    int tid = blockIdx.x * blockDim.x + threadIdx.x;   // grid 192x256 = 49152
    if (tid < 1024) {
        int lo = 0, hi = N;
        while (lo < hi) { int mid = (lo + hi) >> 1; if (bidx[mid] < tid) lo = mid + 1; else hi = mid; }
        int s0 = lo;
        lo = 0; hi = N;
        int v1 = tid + 1;
        while (lo < hi) { int mid = (lo + hi) >> 1; if (bidx[mid] < v1) lo = mid + 1; else hi = mid; }
        starts[tid] = s0;
        counts[tid] = lo - s0;
    }
    {   // 49152 float4s of in_proj_w (768x256)
        float4 v = ((const float4*)w_in)[tid];
        ushort4 o; o.x = f2bf(v.x); o.y = f2bf(v.y); o.z = f2bf(v.z); o.w = f2bf(v.w);
        ((ushort4*)w_in_bf)[tid] = o;
    }
    if (tid < 16384) {  // float4s of out_proj_w (256x256)
        float4 v = ((const float4*)w_out)[tid];
        ushort4 o; o.x = f2bf(v.x); o.y = f2bf(v.y); o.z = f2bf(v.z); o.w = f2bf(v.w);
        ((ushort4*)w_out_bf)[tid] = o;
    }
    if (xbf) {          // X (N x 256 f32) -> bf16, 8 elems per iter, grid-stride
        int total = N * 32;                       // bf16x8 units
        for (int i = tid; i < total; i += 49152) {
            float4 v0 = ((const float4*)X)[2 * i];
            float4 v1 = ((const float4*)X)[2 * i + 1];
            bf16x8 o;
            o[0] = (short)f2bf(v0.x); o[1] = (short)f2bf(v0.y);
            o[2] = (short)f2bf(v0.z); o[3] = (short)f2bf(v0.w);
            o[4] = (short)f2bf(v1.x); o[5] = (short)f2bf(v1.y);
            o[6] = (short)f2bf(v1.z); o[7] = (short)f2bf(v1.w);
            ((bf16x8*)xbf)[i] = o;
        }
    }
}

// ---------------------------------------------------------------------------
// Fused graph-attention v6: 8 waves (512 thr) per graph, 2 blocks/CU.
// Spill diagnosis (v4/v5): under (512,4) the allocator splits 128 regs into
// 64 arch VGPR + 64 AGPR; long-lived vector ARRAYS (afr[2][8] = 64 dwords)
// are spilled to scratch, not promoted to AGPR -> ~100+ MB/dispatch HBM
// scratch traffic (WRITE 159/192 MB vs 80 ideal).
// Fix: QKV repartitioned one step finer. Wave (ws = w&3, th = w>>2) owns ONE
// st (16 rows, afr[8] = 32 regs, reloaded per group from L2-hot xbf ->
// transient) and the 6 tiles j == th (mod 2). Every (tile,st) computed once;
// each B-tile read by 4 waves (2x v4's L2 reads, well under L2 BW).
// Peak reg use per phase: QKV ~60, attn ~55, phase4 ~90 -> no spill.
// Attention/p_s/cs[264]/wout/phase-4 identical to v5.
// ---------------------------------------------------------------------------
__global__ __launch_bounds__(512, 4) void gat_kernel(
    const float* __restrict__ X, const u16* __restrict__ xbf,
    const float* __restrict__ bias_in, const float* __restrict__ bias_out,
    const int* __restrict__ starts, const int* __restrict__ counts,
    const u16* __restrict__ w_in_bf, const u16* __restrict__ w_out_bf,
    float* __restrict__ out, float* __restrict__ wout) {

    __shared__ u16 qg[64][72];       // q for current head pair [node][dim0..63]
    __shared__ u16 kg[64][72];       // k for current head pair
    __shared__ u16 vt[64][72];       // v transposed [dim0..63][key]
    __shared__ u16 p_s[8][16][72];   // per-wave P scratch; reused as f32 wout staging
    __shared__ u16 cs[64][264];      // ctx staging [node][all 256 dims], persists

    const int b = blockIdx.x;
    const int tid = threadIdx.x;
    const int w = tid >> 6;          // 0..7
    const int lane = tid & 63;
    const int n = lane & 15;         // MFMA col / B-row index
    const int quad = lane >> 4;      // MFMA quad
    const int s = starts[b];
    const int c = counts[b];

    const int ws = w & 3;            // QKV st (16-row tile) owner
    const int th = w >> 2;           // QKV tile-half (j parity)
    const int hh = w & 1;            // attn head-in-pair
    const int rt = w >> 1;           // attn row-tile
    const int m0 = rt * 16;

    const float scale = 0.17677669529663687f;  // 1/sqrt(32)
    float wacc[4][4];                // head-mean acc, key = t*16+quad*4+r, query = m0+n
    #pragma unroll
    for (int t = 0; t < 4; ++t)
        #pragma unroll
        for (int r = 0; r < 4; ++r) wacc[t][r] = 0.f;

    // ---- Phase 2+3: head-pair groups ----
    #pragma unroll 1
    for (int g = 0; g < 4; ++g) {
        // this wave's 16 X rows (st = ws) as A-frags, reloaded per group (transient)
        bf16x8 afr[8];
        {
            const int row = ws * 16 + n;
            const bool ok = row < c;
            if (xbf) {
                const u16* src = xbf + (long)(s + row) * 256 + quad * 8;
                #pragma unroll
                for (int ks = 0; ks < 8; ++ks) {
                    bf16x8 a = (bf16x8){0, 0, 0, 0, 0, 0, 0, 0};
                    if (ok) a = *(const bf16x8*)(src + ks * 32);
                    afr[ks] = a;
                }
            } else {   // fallback: convert f32 on the fly (ws too small for xbf)
                const float* src = X + (long)(s + row) * 256 + quad * 8;
                #pragma unroll
                for (int ks = 0; ks < 8; ++ks) {
                    float4 v0 = make_float4(0.f, 0.f, 0.f, 0.f);
                    float4 v1 = make_float4(0.f, 0.f, 0.f, 0.f);
                    if (ok) {
                        v0 = *(const float4*)(src + ks * 32);
                        v1 = *(const float4*)(src + ks * 32 + 4);
                    }
                    bf16x8 a;
                    a[0] = (short)f2bf(v0.x); a[1] = (short)f2bf(v0.y);
                    a[2] = (short)f2bf(v0.z); a[3] = (short)f2bf(v0.w);
                    a[4] = (short)f2bf(v1.x); a[5] = (short)f2bf(v1.y);
                    a[6] = (short)f2bf(v1.z); a[7] = (short)f2bf(v1.w);
                    afr[ks] = a;
                }
            }
        }

        // QKV: 6 tiles j = 2*i + th (type = j>>2, sub = j&3), single st = ws
        #pragma unroll 1
        for (int i = 0; i < 6; ++i) {
            const int j = 2 * i + th;
            const int type = j >> 2;
            const int sub = j & 3;
            const int wrow = type * 256 + g * 64 + sub * 16 + n;
            const u16* wr = w_in_bf + wrow * 256 + quad * 8;
            const float bias = bias_in[wrow];

            f32x4 acc = (f32x4){0.f, 0.f, 0.f, 0.f};
            #pragma unroll
            for (int kh = 0; kh < 2; ++kh) {    // bfr halves (reg pressure)
                bf16x8 bfr[4];
                #pragma unroll
                for (int k4 = 0; k4 < 4; ++k4) bfr[k4] = *(const bf16x8*)(wr + (kh * 4 + k4) * 32);
                #pragma unroll
                for (int k4 = 0; k4 < 4; ++k4) acc = MFMA16(afr[kh * 4 + k4], bfr[k4], acc);
            }

            if (type == 2) {                       // v: transposed, 4 keys packed
                ushort4 pk;
                pk.x = f2bf(acc[0] + bias); pk.y = f2bf(acc[1] + bias);
                pk.z = f2bf(acc[2] + bias); pk.w = f2bf(acc[3] + bias);
                *(ushort4*)&vt[sub * 16 + n][ws * 16 + quad * 4] = pk;
            } else {                               // q/k: row-major
                u16 (*dst)[72] = type ? kg : qg;
                #pragma unroll
                for (int r = 0; r < 4; ++r)
                    dst[ws * 16 + quad * 4 + r][sub * 16 + n] = f2bf(acc[r] + bias);
            }
        }
        __syncthreads();

        // attention: wave (hh, rt) does head g*2+hh for query rows [m0, m0+16)
        // SWAPPED: C[key][query]; lane (n,quad) holds query m0+n, keys
        // t*16+quad*4+r. Full key set spans lanes {n, n^16, n^32, n^48}
        // -> cross-quad reduce via __shfl_xor d=16,32.
        {
            const int h = g * 2 + hh;
            bf16x8 aq = *(const bf16x8*)&qg[m0 + n][hh * 32 + quad * 8];
            f32x4 sc[4];
            #pragma unroll
            for (int t = 0; t < 4; ++t) {
                bf16x8 bk = *(const bf16x8*)&kg[t * 16 + n][hh * 32 + quad * 8];
                f32x4 z = (f32x4){0.f, 0.f, 0.f, 0.f};
                sc[t] = MFMA16(bk, aq, z);         // A=K tile, B=Q -> C[key][query]
            }
            float pv[4][4];
            float mx = -1e30f;
            #pragma unroll
            for (int t = 0; t < 4; ++t)
                #pragma unroll
                for (int r = 0; r < 4; ++r) {
                    float sv = ((t * 16 + quad * 4 + r) < c) ? sc[t][r] * scale : -1e30f;
                    pv[t][r] = sv;
                    mx = fmaxf(mx, sv);
                }
            mx = fmaxf(mx, __shfl_xor(mx, 16, 64));   // cross-quad max (BEFORE exp)
            mx = fmaxf(mx, __shfl_xor(mx, 32, 64));
            float sm = 0.f;
            #pragma unroll
            for (int t = 0; t < 4; ++t)
                #pragma unroll
                for (int r = 0; r < 4; ++r) {
                    float e = ((t * 16 + quad * 4 + r) < c) ? __expf(pv[t][r] - mx) : 0.f;
                    pv[t][r] = e; sm += e;
                }
            sm += __shfl_xor(sm, 16, 64);             // cross-quad sum
            sm += __shfl_xor(sm, 32, 64);
            float invs = 1.f / sm;                    // per-query scalar
            #pragma unroll
            for (int t = 0; t < 4; ++t)
                #pragma unroll
                for (int r = 0; r < 4; ++r) {
                    pv[t][r] *= invs;                 // pre-normalized P
                    wacc[t][r] += pv[t][r] * 0.125f;
                }
            // P^ -> p_s[query][key] (A-layout for PV), 4 ushort4 writes
            #pragma unroll
            for (int t = 0; t < 4; ++t) {
                ushort4 pk;
                pk.x = f2bf(pv[t][0]); pk.y = f2bf(pv[t][1]);
                pk.z = f2bf(pv[t][2]); pk.w = f2bf(pv[t][3]);
                *(ushort4*)&p_s[w][n][t * 16 + quad * 4] = pk;
            }
            // ctx strip = P^.V (already normalized) into cs
            #pragma unroll
            for (int nt = 0; nt < 2; ++nt) {
                f32x4 acc = (f32x4){0.f, 0.f, 0.f, 0.f};
                #pragma unroll
                for (int k2 = 0; k2 < 2; ++k2) {
                    bf16x8 ap = *(const bf16x8*)&p_s[w][n][k2 * 32 + quad * 8];
                    bf16x8 bv = *(const bf16x8*)&vt[hh * 32 + nt * 16 + n][k2 * 32 + quad * 8];
                    acc = MFMA16(ap, bv, acc);
                }
                #pragma unroll
                for (int r = 0; r < 4; ++r)
                    cs[m0 + quad * 4 + r][h * 32 + nt * 16 + n] = f2bf(acc[r]);
            }
        }
        __syncthreads();   // before next group overwrites qg/kg/vt; covers cs for phase 4
    }

    // ---- weights output: head-mean attn [B,64,64], pair-sum across hh ----
    // wacc: key = t*16+quad*4+r for query m0+n. even wave stages f32, odd adds+stores.
    {
        float* pw = (float*)&p_s[w & ~1][0][0];   // two wave slots = 4608 B; stride 72 floats
        if (hh == 0) {
            #pragma unroll
            for (int t = 0; t < 4; ++t) {
                float4 f4 = make_float4(wacc[t][0], wacc[t][1], wacc[t][2], wacc[t][3]);
                *(float4*)&pw[n * 72 + t * 16 + quad * 4] = f4;
            }
        }
        __syncthreads();
        if (hh == 1) {
            #pragma unroll
            for (int t = 0; t < 4; ++t) {
                float4 f4 = *(const float4*)&pw[n * 72 + t * 16 + quad * 4];
                float4 o;
                o.x = wacc[t][0] + f4.x; o.y = wacc[t][1] + f4.y;
                o.z = wacc[t][2] + f4.z; o.w = wacc[t][3] + f4.w;
                *(float4*)&wout[b * 4096 + (m0 + n) * 64 + t * 16 + quad * 4] = o;
            }
        }
    }

    // ---- Phase 4: out = ctx @ W_out^T + b_out, written [L, B, E] ----
    // wave (sp = w&1, cq = w>>1): st in {2sp, 2sp+1}, ct in {4cq .. 4cq+3}
    {
        const int sp = w & 1;
        const int cq = w >> 1;
        bf16x8 actx[2][8];                        // transient (phase-local)
        #pragma unroll
        for (int st2 = 0; st2 < 2; ++st2)
            #pragma unroll
            for (int ks = 0; ks < 8; ++ks)
                actx[st2][ks] = *(const bf16x8*)&cs[(2 * sp + st2) * 16 + n][ks * 32 + quad * 8];

        #pragma unroll 2
        for (int ci = 0; ci < 4; ++ci) {
            const int ct = 4 * cq + ci;
            const u16* wr = w_out_bf + (ct * 16 + n) * 256 + quad * 8;
            f32x4 acc[2];
            acc[0] = (f32x4){0.f, 0.f, 0.f, 0.f};
            acc[1] = (f32x4){0.f, 0.f, 0.f, 0.f};
            #pragma unroll
            for (int kh = 0; kh < 2; ++kh) {
                bf16x8 bfr[4];
                #pragma unroll
                for (int k4 = 0; k4 < 4; ++k4) bfr[k4] = *(const bf16x8*)(wr + (kh * 4 + k4) * 32);
                #pragma unroll
                for (int k4 = 0; k4 < 4; ++k4) {
                    acc[0] = MFMA16(actx[0][kh * 4 + k4], bfr[k4], acc[0]);
                    acc[1] = MFMA16(actx[1][kh * 4 + k4], bfr[k4], acc[1]);
                }
            }
            float bias = bias_out[ct * 16 + n];
            #pragma unroll
            for (int st2 = 0; st2 < 2; ++st2) {
                const int orow = (2 * sp + st2) * 16 + quad * 4;
                #pragma unroll
                for (int r = 0; r < 4; ++r)
                    out[(orow + r) * 262144 + b * 256 + ct * 16 + n] = acc[st2][r] + bias;
            }
        }
    }
}

// ---------------------------------------------------------------------------
extern "C" void kernel_launch(void* const* d_in, const int* in_sizes, int n_in,
                              void* d_out, int out_size, void* d_ws, size_t ws_size,
                              hipStream_t stream) {
    const float* X     = (const float*)d_in[0];
    const int*   bidx  = (const int*)d_in[1];
    const float* w_in  = (const float*)d_in[2];
    const float* b_in  = (const float*)d_in[3];
    const float* w_out = (const float*)d_in[4];
    const float* b_out = (const float*)d_in[5];
    const int N = in_sizes[1];

    float* out  = (float*)d_out;                 // [64, 1024, 256]
    float* wout = out + 64 * 1024 * 256;         // [1024, 64, 64]

    int* starts   = (int*)d_ws;
    int* counts   = starts + 1024;
    u16* w_in_bf  = (u16*)(counts + 1024);       // 768x256 bf16
    u16* w_out_bf = w_in_bf + 196608;            // 256x256 bf16
    u16* xbf      = w_out_bf + 65536;            // N x 256 bf16 (optional)

    const size_t base_need = 2048ull * 4 + 196608ull * 2 + 65536ull * 2;
    const size_t xbf_bytes = (size_t)N * 256 * 2;
    if (ws_size < base_need + xbf_bytes) xbf = nullptr;   // fallback: f32 path in gat

    hipLaunchKernelGGL(prep_kernel, dim3(192), dim3(256), 0, stream,
                       bidx, N, X, w_in, w_out, starts, counts, w_in_bf, w_out_bf, xbf);
    hipLaunchKernelGGL(gat_kernel, dim3(1024), dim3(512), 0, stream,
                       X, xbf, b_in, b_out, starts, counts, w_in_bf, w_out_bf, out, wout);
}

// Round 7
// 298.431 us; speedup vs baseline: 1.2925x; 1.2925x over previous
//
#include <hip/hip_runtime.h>

typedef unsigned short u16;
typedef short bf16x8 __attribute__((ext_vector_type(8)));
typedef float f32x4 __attribute__((ext_vector_type(4)));

#define MFMA16(a, b, c) __builtin_amdgcn_mfma_f32_16x16x32_bf16((a), (b), (c), 0, 0, 0)

// Inter-kernel staging (BSS, zero-init at module load; no ws_size dependence).
// Layouts chosen so attention loads MFMA fragments directly:
//   g_q, g_k: [b][h][row 64][dim 32]   g_vt: [b][h][dim 32][key 64]
__device__ u16 g_q[1024 * 8 * 64 * 32];    // 32 MB
__device__ u16 g_k[1024 * 8 * 64 * 32];    // 32 MB
__device__ u16 g_vt[1024 * 8 * 32 * 64];   // 32 MB

static __device__ __forceinline__ u16 f2bf(float f) {
    union { float f; unsigned int u; } v; v.f = f;
    unsigned int u = v.u;
    u += 0x7fffu + ((u >> 16) & 1u);   // round-to-nearest-even
    return (u16)(u >> 16);
}

// ---------------------------------------------------------------------------
// Prep: starts/counts via binary search + weights->bf16 + X->bf16 (if ws fits)
// ---------------------------------------------------------------------------
__global__ void prep_kernel(const int* __restrict__ bidx, int N,
                            const float* __restrict__ X,
                            const float* __restrict__ w_in, const float* __restrict__ w_out,
                            int* __restrict__ starts, int* __restrict__ counts,
                            u16* __restrict__ w_in_bf, u16* __restrict__ w_out_bf,
                            u16* __restrict__ xbf) {
    int tid = blockIdx.x * blockDim.x + threadIdx.x;   // grid 192x256 = 49152
    if (tid < 1024) {
        int lo = 0, hi = N;
        while (lo < hi) { int mid = (lo + hi) >> 1; if (bidx[mid] < tid) lo = mid + 1; else hi = mid; }
        int s0 = lo;
        lo = 0; hi = N;
        int v1 = tid + 1;
        while (lo < hi) { int mid = (lo + hi) >> 1; if (bidx[mid] < v1) lo = mid + 1; else hi = mid; }
        starts[tid] = s0;
        counts[tid] = lo - s0;
    }
    {   // 49152 float4s of in_proj_w (768x256)
        float4 v = ((const float4*)w_in)[tid];
        ushort4 o; o.x = f2bf(v.x); o.y = f2bf(v.y); o.z = f2bf(v.z); o.w = f2bf(v.w);
        ((ushort4*)w_in_bf)[tid] = o;
    }
    if (tid < 16384) {  // float4s of out_proj_w (256x256)
        float4 v = ((const float4*)w_out)[tid];
        ushort4 o; o.x = f2bf(v.x); o.y = f2bf(v.y); o.z = f2bf(v.z); o.w = f2bf(v.w);
        ((ushort4*)w_out_bf)[tid] = o;
    }
    if (xbf) {          // X (N x 256 f32) -> bf16, 8 elems per iter, grid-stride
        int total = N * 32;                       // bf16x8 units
        for (int i = tid; i < total; i += 49152) {
            float4 v0 = ((const float4*)X)[2 * i];
            float4 v1 = ((const float4*)X)[2 * i + 1];
            bf16x8 o;
            o[0] = (short)f2bf(v0.x); o[1] = (short)f2bf(v0.y);
            o[2] = (short)f2bf(v0.z); o[3] = (short)f2bf(v0.w);
            o[4] = (short)f2bf(v1.x); o[5] = (short)f2bf(v1.y);
            o[6] = (short)f2bf(v1.z); o[7] = (short)f2bf(v1.w);
            ((bf16x8*)xbf)[i] = o;
        }
    }
}

// ---------------------------------------------------------------------------
// v7 kernel A: QKV GEMM. One block (4 waves) per graph; ZERO LDS, ZERO
// barriers. (256,2) -> 256-reg budget: afr[4][8] (128 VGPR) resident with no
// spill (the v2/round-0-proven regime; the 128-cap (512,4) regime spilled).
// Wave w owns col-tiles j = w + 4i (type i = q/k/v, 16-col chunk w) for all
// 4 head-pair groups; 12 independent tile-iters pipeline loads under MFMAs.
// Pad rows (row >= c) use zero A-frags -> outputs = bias (matches reference).
// ---------------------------------------------------------------------------
__global__ __launch_bounds__(256, 2) void qkv_kernel(
    const float* __restrict__ X, const u16* __restrict__ xbf,
    const float* __restrict__ bias_in,
    const int* __restrict__ starts, const int* __restrict__ counts,
    const u16* __restrict__ w_in_bf) {

    const int b = blockIdx.x;
    const int tid = threadIdx.x;
    const int w = tid >> 6;          // 0..3
    const int lane = tid & 63;
    const int n = lane & 15;
    const int quad = lane >> 4;
    const int s = starts[b];
    const int c = counts[b];

    // all 64 rows of this graph as A-frags (zero-pad rows >= c)
    bf16x8 afr[4][8];
    #pragma unroll
    for (int st = 0; st < 4; ++st) {
        const int row = st * 16 + n;
        const bool ok = row < c;
        if (xbf) {
            const u16* src = xbf + (long)(s + row) * 256 + quad * 8;
            #pragma unroll
            for (int ks = 0; ks < 8; ++ks) {
                bf16x8 a = (bf16x8){0, 0, 0, 0, 0, 0, 0, 0};
                if (ok) a = *(const bf16x8*)(src + ks * 32);
                afr[st][ks] = a;
            }
        } else {   // fallback: convert f32 on the fly
            const float* src = X + (long)(s + row) * 256 + quad * 8;
            #pragma unroll
            for (int ks = 0; ks < 8; ++ks) {
                float4 v0 = make_float4(0.f, 0.f, 0.f, 0.f);
                float4 v1 = make_float4(0.f, 0.f, 0.f, 0.f);
                if (ok) {
                    v0 = *(const float4*)(src + ks * 32);
                    v1 = *(const float4*)(src + ks * 32 + 4);
                }
                bf16x8 a;
                a[0] = (short)f2bf(v0.x); a[1] = (short)f2bf(v0.y);
                a[2] = (short)f2bf(v0.z); a[3] = (short)f2bf(v0.w);
                a[4] = (short)f2bf(v1.x); a[5] = (short)f2bf(v1.y);
                a[6] = (short)f2bf(v1.z); a[7] = (short)f2bf(v1.w);
                afr[st][ks] = a;
            }
        }
    }

    const int hw  = w >> 1;          // head-in-pair this wave's cols belong to
    const int dlo = (w & 1) * 16;    // dim offset within the head (0 or 16)

    #pragma unroll 1
    for (int g = 0; g < 4; ++g) {
        for (int i = 0; i < 3; ++i) {            // i = type: 0=q, 1=k, 2=v
            const int wrow = i * 256 + g * 64 + w * 16 + n;
            const u16* wr = w_in_bf + wrow * 256 + quad * 8;
            const float bias = bias_in[wrow];

            bf16x8 bfr[8];
            #pragma unroll
            for (int ks = 0; ks < 8; ++ks) bfr[ks] = *(const bf16x8*)(wr + ks * 32);

            f32x4 acc[4];
            #pragma unroll
            for (int st = 0; st < 4; ++st) acc[st] = (f32x4){0.f, 0.f, 0.f, 0.f};
            #pragma unroll
            for (int ks = 0; ks < 8; ++ks)
                #pragma unroll
                for (int st = 0; st < 4; ++st)
                    acc[st] = MFMA16(afr[st][ks], bfr[ks], acc[st]);

            const int h = g * 2 + hw;
            if (i == 2) {                         // v -> g_vt[b][h][dim][key]
                u16* vd = g_vt + ((long)(b * 8 + h) * 32 + dlo + n) * 64;
                #pragma unroll
                for (int st = 0; st < 4; ++st) {
                    ushort4 pk;
                    pk.x = f2bf(acc[st][0] + bias); pk.y = f2bf(acc[st][1] + bias);
                    pk.z = f2bf(acc[st][2] + bias); pk.w = f2bf(acc[st][3] + bias);
                    *(ushort4*)&vd[st * 16 + quad * 4] = pk;
                }
            } else {                              // q/k -> [b][h][row][dim]
                u16* dst = (i == 0 ? g_q : g_k) + (long)(b * 8 + h) * 2048;
                #pragma unroll
                for (int st = 0; st < 4; ++st)
                    #pragma unroll
                    for (int r = 0; r < 4; ++r)
                        dst[(st * 16 + quad * 4 + r) * 32 + dlo + n] = f2bf(acc[st][r] + bias);
            }
        }
    }
}

// ---------------------------------------------------------------------------
// v7 kernel B: attention + head-mean weights + out-projection.
// One block (8 waves) per graph. Q/K/V fragments load DIRECTLY from the
// per-head global buffers (L2/L3-hot) -> no qg/kg/vt staging, and the g-loop
// has ZERO barriers (p_s is wave-private; cs regions are disjoint per wave).
// Only 2 __syncthreads total (cs ready; wout pair-exchange).
// LDS 52224 B. (512,4): 128-reg cap; peak live ~80 regs -> no spill.
// ---------------------------------------------------------------------------
__global__ __launch_bounds__(512, 4) void attn_kernel(
    const float* __restrict__ bias_out, const int* __restrict__ counts,
    const u16* __restrict__ w_out_bf,
    float* __restrict__ out, float* __restrict__ wout) {

    __shared__ u16 p_s[8][16][72];   // per-wave P scratch; reused as f32 wout staging
    __shared__ u16 cs[64][264];      // ctx staging [node][all 256 dims]

    const int b = blockIdx.x;
    const int tid = threadIdx.x;
    const int w = tid >> 6;          // 0..7
    const int lane = tid & 63;
    const int n = lane & 15;
    const int quad = lane >> 4;
    const int c = counts[b];

    const int hh = w & 1;            // head-in-pair
    const int rt = w >> 1;           // query row-tile
    const int m0 = rt * 16;

    const float scale = 0.17677669529663687f;  // 1/sqrt(32)
    float wacc[4][4];                // key = t*16+quad*4+r, query = m0+n
    #pragma unroll
    for (int t = 0; t < 4; ++t)
        #pragma unroll
        for (int r = 0; r < 4; ++r) wacc[t][r] = 0.f;

    // ---- attention, 4 independent head iterations, no barriers ----
    #pragma unroll 1
    for (int g = 0; g < 4; ++g) {
        const int h = g * 2 + hh;
        const u16* qh = g_q  + (long)(b * 8 + h) * 2048;   // [row][32]
        const u16* kh = g_k  + (long)(b * 8 + h) * 2048;   // [row][32]
        const u16* vh = g_vt + (long)(b * 8 + h) * 2048;   // [dim][64]

        bf16x8 aq = *(const bf16x8*)&qh[(m0 + n) * 32 + quad * 8];
        f32x4 sc[4];
        #pragma unroll
        for (int t = 0; t < 4; ++t) {
            bf16x8 bk = *(const bf16x8*)&kh[(t * 16 + n) * 32 + quad * 8];
            f32x4 z = (f32x4){0.f, 0.f, 0.f, 0.f};
            sc[t] = MFMA16(bk, aq, z);             // swapped: C[key][query]
        }
        float pv[4][4];
        float mx = -1e30f;
        #pragma unroll
        for (int t = 0; t < 4; ++t)
            #pragma unroll
            for (int r = 0; r < 4; ++r) {
                float sv = ((t * 16 + quad * 4 + r) < c) ? sc[t][r] * scale : -1e30f;
                pv[t][r] = sv;
                mx = fmaxf(mx, sv);
            }
        mx = fmaxf(mx, __shfl_xor(mx, 16, 64));    // cross-quad max (before exp)
        mx = fmaxf(mx, __shfl_xor(mx, 32, 64));
        float sm = 0.f;
        #pragma unroll
        for (int t = 0; t < 4; ++t)
            #pragma unroll
            for (int r = 0; r < 4; ++r) {
                float e = ((t * 16 + quad * 4 + r) < c) ? __expf(pv[t][r] - mx) : 0.f;
                pv[t][r] = e; sm += e;
            }
        sm += __shfl_xor(sm, 16, 64);              // cross-quad sum
        sm += __shfl_xor(sm, 32, 64);
        float invs = 1.f / sm;
        #pragma unroll
        for (int t = 0; t < 4; ++t)
            #pragma unroll
            for (int r = 0; r < 4; ++r) {
                pv[t][r] *= invs;                  // pre-normalized P
                wacc[t][r] += pv[t][r] * 0.125f;
            }
        // P: C-layout -> A-layout via wave-private LDS (lgkmcnt only, no barrier)
        #pragma unroll
        for (int t = 0; t < 4; ++t) {
            ushort4 pk;
            pk.x = f2bf(pv[t][0]); pk.y = f2bf(pv[t][1]);
            pk.z = f2bf(pv[t][2]); pk.w = f2bf(pv[t][3]);
            *(ushort4*)&p_s[w][n][t * 16 + quad * 4] = pk;
        }
        // ctx strip = P.V -> cs (disjoint region per wave)
        #pragma unroll
        for (int nt = 0; nt < 2; ++nt) {
            f32x4 acc = (f32x4){0.f, 0.f, 0.f, 0.f};
            #pragma unroll
            for (int k2 = 0; k2 < 2; ++k2) {
                bf16x8 ap = *(const bf16x8*)&p_s[w][n][k2 * 32 + quad * 8];
                bf16x8 bv = *(const bf16x8*)&vh[(nt * 16 + n) * 64 + k2 * 32 + quad * 8];
                acc = MFMA16(ap, bv, acc);
            }
            #pragma unroll
            for (int r = 0; r < 4; ++r)
                cs[m0 + quad * 4 + r][h * 32 + nt * 16 + n] = f2bf(acc[r]);
        }
    }
    __syncthreads();   // cs complete; p_s free for reuse

    // ---- weights output: head-mean attn [B,64,64], pair-sum across hh ----
    {
        float* pw = (float*)&p_s[w & ~1][0][0];   // pair slot = 4608 B
        if (hh == 0) {
            #pragma unroll
            for (int t = 0; t < 4; ++t) {
                float4 f4 = make_float4(wacc[t][0], wacc[t][1], wacc[t][2], wacc[t][3]);
                *(float4*)&pw[n * 72 + t * 16 + quad * 4] = f4;
            }
        }
        __syncthreads();
        if (hh == 1) {
            #pragma unroll
            for (int t = 0; t < 4; ++t) {
                float4 f4 = *(const float4*)&pw[n * 72 + t * 16 + quad * 4];
                float4 o;
                o.x = wacc[t][0] + f4.x; o.y = wacc[t][1] + f4.y;
                o.z = wacc[t][2] + f4.z; o.w = wacc[t][3] + f4.w;
                *(float4*)&wout[b * 4096 + (m0 + n) * 64 + t * 16 + quad * 4] = o;
            }
        }
    }

    // ---- out = ctx @ W_out^T + b_out, written [L, B, E] ----
    // wave: st = w&3, ct in {8*(w>>2) .. +7}; actx[8] = 32 regs (transient)
    {
        const int sp = w & 3;
        const int cq = w >> 2;
        bf16x8 actx[8];
        #pragma unroll
        for (int ks = 0; ks < 8; ++ks)
            actx[ks] = *(const bf16x8*)&cs[sp * 16 + n][ks * 32 + quad * 8];

        #pragma unroll 2
        for (int ci = 0; ci < 8; ++ci) {
            const int ct = cq * 8 + ci;
            const u16* wr = w_out_bf + (ct * 16 + n) * 256 + quad * 8;
            f32x4 acc = (f32x4){0.f, 0.f, 0.f, 0.f};
            #pragma unroll
            for (int kh = 0; kh < 2; ++kh) {
                bf16x8 bfr[4];
                #pragma unroll
                for (int k4 = 0; k4 < 4; ++k4) bfr[k4] = *(const bf16x8*)(wr + (kh * 4 + k4) * 32);
                #pragma unroll
                for (int k4 = 0; k4 < 4; ++k4) acc = MFMA16(actx[kh * 4 + k4], bfr[k4], acc);
            }
            const float bias = bias_out[ct * 16 + n];
            const int orow = sp * 16 + quad * 4;
            #pragma unroll
            for (int r = 0; r < 4; ++r)
                out[(orow + r) * 262144 + b * 256 + ct * 16 + n] = acc[r] + bias;
        }
    }
}

// ---------------------------------------------------------------------------
extern "C" void kernel_launch(void* const* d_in, const int* in_sizes, int n_in,
                              void* d_out, int out_size, void* d_ws, size_t ws_size,
                              hipStream_t stream) {
    const float* X     = (const float*)d_in[0];
    const int*   bidx  = (const int*)d_in[1];
    const float* w_in  = (const float*)d_in[2];
    const float* b_in  = (const float*)d_in[3];
    const float* w_out = (const float*)d_in[4];
    const float* b_out = (const float*)d_in[5];
    const int N = in_sizes[1];

    float* out  = (float*)d_out;                 // [64, 1024, 256]
    float* wout = out + 64 * 1024 * 256;         // [1024, 64, 64]

    int* starts   = (int*)d_ws;
    int* counts   = starts + 1024;
    u16* w_in_bf  = (u16*)(counts + 1024);       // 768x256 bf16
    u16* w_out_bf = w_in_bf + 196608;            // 256x256 bf16
    u16* xbf      = w_out_bf + 65536;            // N x 256 bf16 (optional)

    const size_t base_need = 2048ull * 4 + 196608ull * 2 + 65536ull * 2;
    const size_t xbf_bytes = (size_t)N * 256 * 2;
    if (ws_size < base_need + xbf_bytes) xbf = nullptr;   // fallback: f32 path in qkv

    hipLaunchKernelGGL(prep_kernel, dim3(192), dim3(256), 0, stream,
                       bidx, N, X, w_in, w_out, starts, counts, w_in_bf, w_out_bf, xbf);
    hipLaunchKernelGGL(qkv_kernel, dim3(1024), dim3(256), 0, stream,
                       X, xbf, b_in, starts, counts, w_in_bf);
    hipLaunchKernelGGL(attn_kernel, dim3(1024), dim3(512), 0, stream,
                       b_out, counts, w_out_bf, out, wout);
}